// Round 5
// baseline (290.706 us; speedup 1.0000x reference)
//
#include <hip/hip_runtime.h>

#define HW_ 262144          // 512*512
#define NCH 32
#define NIMG 4
#define NCLS 19
#define ALPHA_ 0.05f
#define BETA_ 1.0f

// workspace float offsets
#define WS_SEG   0          // [4][19][32] class sums
#define WS_CNT   2432       // [4][19]     class counts
#define WS_MEAN  2508       // [4][19][32] class means
#define WS_MNORM 4940       // [4][19]     ||mean||^2 per class
#define WS_INUM  5016       // [4] intra numerator
#define WS_ICNT  5020       // [4] intra valid count
#define WS_IVAL  5024       // [4] per-image inter value
#define WS_ZERO_FLOATS 5028

#define REP 2

// ---------------- k_seg: class sums of normalized embeddings + counts --------
// Channel-major contiguous streaming: block owns a contiguous 512-px span;
// per channel the block reads one contiguous 2KB chunk (wave: 64 lanes x
// float2, perfectly coalesced). Two c-loops: (1) sum-of-squares in registers,
// (2) re-read (L3-warm) and scatter v*rn via hw ds_add_f32.
__global__ __launch_bounds__(256) void k_seg(const float* __restrict__ emb,
                                             const int* __restrict__ lab,
                                             float* __restrict__ ws)
{
    const int n = blockIdx.y;
    __shared__ float seg[REP][NCLS][33];
    __shared__ float scnt[REP][NCLS];
    for (int t = threadIdx.x; t < REP * NCLS * 33; t += 256) (&seg[0][0][0])[t] = 0.f;
    if (threadIdx.x < REP * NCLS) (&scnt[0][0])[threadIdx.x] = 0.f;
    __syncthreads();

    const float* eb = emb + (size_t)n * NCH * HW_;
    const int p = blockIdx.x * 512 + 2 * threadIdx.x;   // contiguous span

    int l0 = lab[n * HW_ + p];
    int l1 = lab[n * HW_ + p + 1];
    if (l0 == 255) l0 = 0;
    if (l1 == 255) l1 = 0;

    // loop 1: sum of squares (8 independent float2 loads in flight per batch)
    float ss0 = 0.f, ss1 = 0.f;
    for (int cb = 0; cb < NCH; cb += 8) {
        float2 u[8];
        #pragma unroll
        for (int k = 0; k < 8; ++k)
            u[k] = *(const float2*)(eb + (size_t)(cb + k) * HW_ + p);
        #pragma unroll
        for (int k = 0; k < 8; ++k) {
            ss0 += u[k].x * u[k].x;
            ss1 += u[k].y * u[k].y;
        }
    }
    float rn0 = 1.f / fmaxf(sqrtf(ss0), 1e-12f);
    float rn1 = 1.f / fmaxf(sqrtf(ss1), 1e-12f);

    const int rep = threadIdx.x & (REP - 1);   // lane-parity replica split
    unsafeAtomicAdd(&scnt[rep][l0], 1.f);
    unsafeAtomicAdd(&scnt[rep][l1], 1.f);

    // loop 2: re-read (L3-warm) and scatter. Banks: (19*rep + l + c) % 32 ->
    // distinct classes hit distinct banks; same class+rep = same-address
    // (avg ~1.7-way with REP=2) handled by ds_add RMW.
    for (int cb = 0; cb < NCH; cb += 8) {
        float2 u[8];
        #pragma unroll
        for (int k = 0; k < 8; ++k)
            u[k] = *(const float2*)(eb + (size_t)(cb + k) * HW_ + p);
        #pragma unroll
        for (int k = 0; k < 8; ++k) {
            unsafeAtomicAdd(&seg[rep][l0][cb + k], u[k].x * rn0);
            unsafeAtomicAdd(&seg[rep][l1][cb + k], u[k].y * rn1);
        }
    }
    __syncthreads();

    // flush block accumulators
    for (int t = threadIdx.x; t < NCLS * NCH; t += 256) {
        int k = t >> 5, c = t & 31;
        float s = 0.f;
        #pragma unroll
        for (int r = 0; r < REP; ++r) s += seg[r][k][c];
        unsafeAtomicAdd(&ws[WS_SEG + n * NCLS * NCH + t], s);
    }
    if (threadIdx.x < NCLS) {
        float s = 0.f;
        #pragma unroll
        for (int r = 0; r < REP; ++r) s += scnt[r][threadIdx.x];
        unsafeAtomicAdd(&ws[WS_CNT + n * NCLS + threadIdx.x], s);
    }
}

// ---------------- k_stats: means, ||mean||^2, D matrix, per-image inter ------
__global__ __launch_bounds__(512) void k_stats(float* __restrict__ ws)
{
    const int n = blockIdx.x;
    __shared__ float smean[NCLS][NCH + 1];
    __shared__ float scnt[NCLS];
    __shared__ float snum, sden;
    if (threadIdx.x == 0) { snum = 0.f; sden = 0.f; }
    for (int t = threadIdx.x; t < NCLS; t += blockDim.x)
        scnt[t] = ws[WS_CNT + n * NCLS + t];
    __syncthreads();

    for (int t = threadIdx.x; t < NCLS * NCH; t += blockDim.x) {
        int k = t >> 5, c = t & 31;
        float m = ws[WS_SEG + n * NCLS * NCH + t] / (scnt[k] + 1.f);
        smean[k][c] = m;
        ws[WS_MEAN + n * NCLS * NCH + t] = m;
    }
    __syncthreads();

    if (threadIdx.x < NCLS) {
        float s = 0.f;
        #pragma unroll
        for (int c = 0; c < NCH; ++c) { float m = smean[threadIdx.x][c]; s += m * m; }
        ws[WS_MNORM + n * NCLS + threadIdx.x] = s;
    }

    for (int t = threadIdx.x; t < NCLS * NCLS; t += blockDim.x) {
        int i = t / NCLS, j = t - i * NCLS;
        float D = 0.f;
        #pragma unroll
        for (int c = 0; c < NCH; ++c) {
            float df = smean[i][c] - smean[j][c];
            D += df * df;
        }
        float pres = (scnt[i] > 0.f && scnt[j] > 0.f) ? 1.f : 0.f;
        D *= pres;
        bool im = (D < BETA_) && (D > 0.f);
        if (i >= 1 && im) {
            unsafeAtomicAdd(&sden, 1.f);
            if (j >= 1) unsafeAtomicAdd(&snum, BETA_ - D);
        }
    }
    __syncthreads();
    if (threadIdx.x == 0)
        ws[WS_IVAL + n] = snum / (sden + 1.f) * 0.5f;
}

// ---------------- k_intra: single-pass via algebraic expansion ----------------
// d = ||m||^2 - 2*(m.v)*rn + ss*rn^2  -> one contiguous channel-major pass,
// register accumulators only.
__global__ __launch_bounds__(256) void k_intra(const float* __restrict__ emb,
                                               const int* __restrict__ lab,
                                               float* __restrict__ ws)
{
    const int n = blockIdx.y;
    __shared__ float smean[NCLS][33];
    __shared__ float smn[NCLS];
    __shared__ float bnum, bcnt;
    for (int t = threadIdx.x; t < NCLS * NCH; t += 256)
        smean[t >> 5][t & 31] = ws[WS_MEAN + n * NCLS * NCH + t];
    if (threadIdx.x < NCLS) smn[threadIdx.x] = ws[WS_MNORM + n * NCLS + threadIdx.x];
    if (threadIdx.x == 0) { bnum = 0.f; bcnt = 0.f; }
    __syncthreads();

    const float* eb = emb + (size_t)n * NCH * HW_;
    const int p = blockIdx.x * 512 + 2 * threadIdx.x;

    int l0 = lab[n * HW_ + p];
    int l1 = lab[n * HW_ + p + 1];
    if (l0 == 255) l0 = 0;
    if (l1 == 255) l1 = 0;

    float ss0 = 0.f, ss1 = 0.f, dot0 = 0.f, dot1 = 0.f;
    for (int cb = 0; cb < NCH; cb += 8) {
        float2 u[8];
        #pragma unroll
        for (int k = 0; k < 8; ++k)
            u[k] = *(const float2*)(eb + (size_t)(cb + k) * HW_ + p);
        #pragma unroll
        for (int k = 0; k < 8; ++k) {
            // lanes: fixed c, varying class -> distinct banks; same class = broadcast
            float m0 = smean[l0][cb + k];
            float m1 = smean[l1][cb + k];
            ss0  += u[k].x * u[k].x;
            ss1  += u[k].y * u[k].y;
            dot0 += u[k].x * m0;
            dot1 += u[k].y * m1;
        }
    }
    float rn0 = 1.f / fmaxf(sqrtf(ss0), 1e-12f);
    float rn1 = 1.f / fmaxf(sqrtf(ss1), 1e-12f);
    float d0 = smn[l0] - 2.f * dot0 * rn0 + ss0 * rn0 * rn0;
    float d1 = smn[l1] - 2.f * dot1 * rn1 + ss1 * rn1 * rn1;

    float lnum = 0.f, lcnt = 0.f;
    if (l0 > 0 && d0 > ALPHA_) { lnum += d0 - ALPHA_; lcnt += 1.f; }
    if (l1 > 0 && d1 > ALPHA_) { lnum += d1 - ALPHA_; lcnt += 1.f; }

    for (int o = 32; o > 0; o >>= 1) {
        lnum += __shfl_down(lnum, o);
        lcnt += __shfl_down(lcnt, o);
    }
    if ((threadIdx.x & 63) == 0) { unsafeAtomicAdd(&bnum, lnum); unsafeAtomicAdd(&bcnt, lcnt); }
    __syncthreads();
    if (threadIdx.x == 0) {
        unsafeAtomicAdd(&ws[WS_INUM + n], bnum);
        unsafeAtomicAdd(&ws[WS_ICNT + n], bcnt);
    }
}

// ---------------- Final scalar combine ---------------------------------------
__global__ void k_final(const float* __restrict__ ws, float* __restrict__ out)
{
    if (threadIdx.x == 0 && blockIdx.x == 0) {
        float intra = 0.f, inter = 0.f;
        for (int n = 0; n < NIMG; ++n) {
            intra += ws[WS_INUM + n] / (ws[WS_ICNT + n] + 1.f);
            inter += ws[WS_IVAL + n];
        }
        out[0] = intra * 0.25f;
        out[1] = inter * 0.25f;
    }
}

extern "C" void kernel_launch(void* const* d_in, const int* in_sizes, int n_in,
                              void* d_out, int out_size, void* d_ws, size_t ws_size,
                              hipStream_t stream)
{
    const float* emb = (const float*)d_in[0];
    const int*   lab = (const int*)d_in[1];
    float* ws  = (float*)d_ws;
    float* out = (float*)d_out;

    hipMemsetAsync(d_ws, 0, WS_ZERO_FLOATS * sizeof(float), stream);

    dim3 g(HW_ / 512, NIMG);   // 512 px per block -> 2048 blocks, 8/CU, 32 waves/CU
    k_seg<<<g, 256, 0, stream>>>(emb, lab, ws);

    k_stats<<<NIMG, 512, 0, stream>>>(ws);

    k_intra<<<g, 256, 0, stream>>>(emb, lab, ws);

    k_final<<<1, 64, 0, stream>>>(ws, out);
}

// Round 6
// 119.672 us; speedup vs baseline: 2.4292x; 2.4292x over previous
//
#include <hip/hip_runtime.h>

#define HW_ 262144          // 512*512
#define NCH 32
#define NIMG 4
#define NCLS 19
#define ALPHA_ 0.05f
#define BETA_ 1.0f

// workspace float offsets
#define WS_SEG   0          // [4][19][32] class sums
#define WS_CNT   2432       // [4][19]     class counts
#define WS_MEAN  2508       // [4][19][32] class means
#define WS_MNORM 4940       // [4][19]     ||mean||^2 per class
#define WS_INUM  5016       // [4] intra numerator
#define WS_ICNT  5020       // [4] intra valid count
#define WS_IVAL  5024       // [4] per-image inter value
#define WS_ZERO_FLOATS 5028

#define REP 2
#define FXS 2097152.0f      // 2^21 fixed-point scale
#define FXI (1.0f/2097152.0f)

// load 4 consecutive channels' float4 (4 pixels) into named buffer
#define LD4(dst, cb) {                                            \
    dst##0 = *(const float4*)(eb + (size_t)((cb)+0) * HW_ + p);   \
    dst##1 = *(const float4*)(eb + (size_t)((cb)+1) * HW_ + p);   \
    dst##2 = *(const float4*)(eb + (size_t)((cb)+2) * HW_ + p);   \
    dst##3 = *(const float4*)(eb + (size_t)((cb)+3) * HW_ + p); }

#define SSACC(v) { ss0 += v.x*v.x; ss1 += v.y*v.y; ss2 += v.z*v.z; ss3 += v.w*v.w; }
#define STEP_SS(b) { SSACC(b##0); SSACC(b##1); SSACC(b##2); SSACC(b##3); }

// ---------------- k_seg: class sums via int32 fixed-point ds_add_u32 ---------
__global__ __launch_bounds__(256) void k_seg(const float* __restrict__ emb,
                                             const int* __restrict__ lab,
                                             float* __restrict__ ws)
{
    const int n = blockIdx.y;
    __shared__ int segi[REP][NCLS][33];
    __shared__ int cnti[REP][NCLS];
    for (int t = threadIdx.x; t < REP * NCLS * 33; t += 256) (&segi[0][0][0])[t] = 0;
    if (threadIdx.x < REP * NCLS) (&cnti[0][0])[threadIdx.x] = 0;
    __syncthreads();

    const float* eb = emb + (size_t)n * NCH * HW_;
    const int p = blockIdx.x * 1024 + 4 * threadIdx.x;   // 4 px per thread

    int4 lv = *(const int4*)(lab + (size_t)n * HW_ + p);
    const int l0 = (lv.x == 255) ? 0 : lv.x;
    const int l1 = (lv.y == 255) ? 0 : lv.y;
    const int l2 = (lv.z == 255) ? 0 : lv.z;
    const int l3 = (lv.w == 255) ? 0 : lv.w;
    const int rep = threadIdx.x & (REP - 1);

    // ---- loop 1: sum of squares, ping-pong pipelined loads ----
    float ss0 = 0.f, ss1 = 0.f, ss2 = 0.f, ss3 = 0.f;
    {
        float4 A0, A1, A2, A3, B0, B1, B2, B3;
        LD4(A, 0);  LD4(B, 4);
        STEP_SS(A); LD4(A, 8);
        STEP_SS(B); LD4(B, 12);
        STEP_SS(A); LD4(A, 16);
        STEP_SS(B); LD4(B, 20);
        STEP_SS(A); LD4(A, 24);
        STEP_SS(B); LD4(B, 28);
        STEP_SS(A); STEP_SS(B);
    }
    const float rn0 = 1.f / fmaxf(sqrtf(ss0), 1e-12f);
    const float rn1 = 1.f / fmaxf(sqrtf(ss1), 1e-12f);
    const float rn2 = 1.f / fmaxf(sqrtf(ss2), 1e-12f);
    const float rn3 = 1.f / fmaxf(sqrtf(ss3), 1e-12f);

    atomicAdd(&cnti[rep][l0], 1);
    atomicAdd(&cnti[rep][l1], 1);
    atomicAdd(&cnti[rep][l2], 1);
    atomicAdd(&cnti[rep][l3], 1);

    // ---- loop 2: re-read (L2/L3-warm) + fixed-point scatter (ds_add_u32) ----
#define SCAT(v, c) {                                                   \
    atomicAdd(&segi[rep][l0][c], __float2int_rn(v.x * rn0 * FXS));     \
    atomicAdd(&segi[rep][l1][c], __float2int_rn(v.y * rn1 * FXS));     \
    atomicAdd(&segi[rep][l2][c], __float2int_rn(v.z * rn2 * FXS));     \
    atomicAdd(&segi[rep][l3][c], __float2int_rn(v.w * rn3 * FXS)); }
#define STEP_SC(b, cb) { SCAT(b##0, (cb)+0); SCAT(b##1, (cb)+1); SCAT(b##2, (cb)+2); SCAT(b##3, (cb)+3); }
    {
        float4 A0, A1, A2, A3, B0, B1, B2, B3;
        LD4(A, 0);      LD4(B, 4);
        STEP_SC(A, 0);  LD4(A, 8);
        STEP_SC(B, 4);  LD4(B, 12);
        STEP_SC(A, 8);  LD4(A, 16);
        STEP_SC(B, 12); LD4(B, 20);
        STEP_SC(A, 16); LD4(A, 24);
        STEP_SC(B, 20); LD4(B, 28);
        STEP_SC(A, 24); STEP_SC(B, 28);
    }
    __syncthreads();

    // flush: int -> float, one global hw atomic per value
    for (int t = threadIdx.x; t < NCLS * NCH; t += 256) {
        int k = t >> 5, c = t & 31;
        float s = (float)(segi[0][k][c] + segi[1][k][c]) * FXI;
        unsafeAtomicAdd(&ws[WS_SEG + n * NCLS * NCH + t], s);
    }
    if (threadIdx.x < NCLS) {
        float s = (float)(cnti[0][threadIdx.x] + cnti[1][threadIdx.x]);
        unsafeAtomicAdd(&ws[WS_CNT + n * NCLS + threadIdx.x], s);
    }
}

// ---------------- k_stats: means, ||mean||^2, D matrix, per-image inter ------
__global__ __launch_bounds__(512) void k_stats(float* __restrict__ ws)
{
    const int n = blockIdx.x;
    __shared__ float smean[NCLS][NCH + 1];
    __shared__ float scnt[NCLS];
    __shared__ float snum, sden;
    if (threadIdx.x == 0) { snum = 0.f; sden = 0.f; }
    for (int t = threadIdx.x; t < NCLS; t += blockDim.x)
        scnt[t] = ws[WS_CNT + n * NCLS + t];
    __syncthreads();

    for (int t = threadIdx.x; t < NCLS * NCH; t += blockDim.x) {
        int k = t >> 5, c = t & 31;
        float m = ws[WS_SEG + n * NCLS * NCH + t] / (scnt[k] + 1.f);
        smean[k][c] = m;
        ws[WS_MEAN + n * NCLS * NCH + t] = m;
    }
    __syncthreads();

    if (threadIdx.x < NCLS) {
        float s = 0.f;
        #pragma unroll
        for (int c = 0; c < NCH; ++c) { float m = smean[threadIdx.x][c]; s += m * m; }
        ws[WS_MNORM + n * NCLS + threadIdx.x] = s;
    }

    for (int t = threadIdx.x; t < NCLS * NCLS; t += blockDim.x) {
        int i = t / NCLS, j = t - i * NCLS;
        float D = 0.f;
        #pragma unroll
        for (int c = 0; c < NCH; ++c) {
            float df = smean[i][c] - smean[j][c];
            D += df * df;
        }
        float pres = (scnt[i] > 0.f && scnt[j] > 0.f) ? 1.f : 0.f;
        D *= pres;
        bool im = (D < BETA_) && (D > 0.f);
        if (i >= 1 && im) {
            unsafeAtomicAdd(&sden, 1.f);
            if (j >= 1) unsafeAtomicAdd(&snum, BETA_ - D);
        }
    }
    __syncthreads();
    if (threadIdx.x == 0)
        ws[WS_IVAL + n] = snum / (sden + 1.f) * 0.5f;
}

// ---------------- k_intra: single pass, pipelined, algebraic expansion -------
__global__ __launch_bounds__(256) void k_intra(const float* __restrict__ emb,
                                               const int* __restrict__ lab,
                                               float* __restrict__ ws)
{
    const int n = blockIdx.y;
    __shared__ float smean[NCLS][33];
    __shared__ float smn[NCLS];
    __shared__ float bnum, bcnt;
    for (int t = threadIdx.x; t < NCLS * NCH; t += 256)
        smean[t >> 5][t & 31] = ws[WS_MEAN + n * NCLS * NCH + t];
    if (threadIdx.x < NCLS) smn[threadIdx.x] = ws[WS_MNORM + n * NCLS + threadIdx.x];
    if (threadIdx.x == 0) { bnum = 0.f; bcnt = 0.f; }
    __syncthreads();

    const float* eb = emb + (size_t)n * NCH * HW_;
    const int p = blockIdx.x * 1024 + 4 * threadIdx.x;

    int4 lv = *(const int4*)(lab + (size_t)n * HW_ + p);
    const int l0 = (lv.x == 255) ? 0 : lv.x;
    const int l1 = (lv.y == 255) ? 0 : lv.y;
    const int l2 = (lv.z == 255) ? 0 : lv.z;
    const int l3 = (lv.w == 255) ? 0 : lv.w;

    float ss0 = 0.f, ss1 = 0.f, ss2 = 0.f, ss3 = 0.f;
    float dt0 = 0.f, dt1 = 0.f, dt2 = 0.f, dt3 = 0.f;
#define DOTACC(v, c) {                                  \
    float m0 = smean[l0][c], m1 = smean[l1][c];         \
    float m2 = smean[l2][c], m3 = smean[l3][c];         \
    ss0 += v.x*v.x; dt0 += v.x*m0;                      \
    ss1 += v.y*v.y; dt1 += v.y*m1;                      \
    ss2 += v.z*v.z; dt2 += v.z*m2;                      \
    ss3 += v.w*v.w; dt3 += v.w*m3; }
#define STEP_DOT(b, cb) { DOTACC(b##0, (cb)+0); DOTACC(b##1, (cb)+1); DOTACC(b##2, (cb)+2); DOTACC(b##3, (cb)+3); }
    {
        float4 A0, A1, A2, A3, B0, B1, B2, B3;
        LD4(A, 0);       LD4(B, 4);
        STEP_DOT(A, 0);  LD4(A, 8);
        STEP_DOT(B, 4);  LD4(B, 12);
        STEP_DOT(A, 8);  LD4(A, 16);
        STEP_DOT(B, 12); LD4(B, 20);
        STEP_DOT(A, 16); LD4(A, 24);
        STEP_DOT(B, 20); LD4(B, 28);
        STEP_DOT(A, 24); STEP_DOT(B, 28);
    }
    const float rn0 = 1.f / fmaxf(sqrtf(ss0), 1e-12f);
    const float rn1 = 1.f / fmaxf(sqrtf(ss1), 1e-12f);
    const float rn2 = 1.f / fmaxf(sqrtf(ss2), 1e-12f);
    const float rn3 = 1.f / fmaxf(sqrtf(ss3), 1e-12f);
    float d0 = smn[l0] - 2.f * dt0 * rn0 + ss0 * rn0 * rn0;
    float d1 = smn[l1] - 2.f * dt1 * rn1 + ss1 * rn1 * rn1;
    float d2 = smn[l2] - 2.f * dt2 * rn2 + ss2 * rn2 * rn2;
    float d3 = smn[l3] - 2.f * dt3 * rn3 + ss3 * rn3 * rn3;

    float lnum = 0.f, lcnt = 0.f;
    if (l0 > 0 && d0 > ALPHA_) { lnum += d0 - ALPHA_; lcnt += 1.f; }
    if (l1 > 0 && d1 > ALPHA_) { lnum += d1 - ALPHA_; lcnt += 1.f; }
    if (l2 > 0 && d2 > ALPHA_) { lnum += d2 - ALPHA_; lcnt += 1.f; }
    if (l3 > 0 && d3 > ALPHA_) { lnum += d3 - ALPHA_; lcnt += 1.f; }

    for (int o = 32; o > 0; o >>= 1) {
        lnum += __shfl_down(lnum, o);
        lcnt += __shfl_down(lcnt, o);
    }
    if ((threadIdx.x & 63) == 0) { unsafeAtomicAdd(&bnum, lnum); unsafeAtomicAdd(&bcnt, lcnt); }
    __syncthreads();
    if (threadIdx.x == 0) {
        unsafeAtomicAdd(&ws[WS_INUM + n], bnum);
        unsafeAtomicAdd(&ws[WS_ICNT + n], bcnt);
    }
}

// ---------------- k_final ----------------------------------------------------
__global__ void k_final(const float* __restrict__ ws, float* __restrict__ out)
{
    if (threadIdx.x == 0 && blockIdx.x == 0) {
        float intra = 0.f, inter = 0.f;
        for (int n = 0; n < NIMG; ++n) {
            intra += ws[WS_INUM + n] / (ws[WS_ICNT + n] + 1.f);
            inter += ws[WS_IVAL + n];
        }
        out[0] = intra * 0.25f;
        out[1] = inter * 0.25f;
    }
}

// ---------------- k_probe: DIAGNOSTIC — loads-only clone of k_seg loop 1 -----
__global__ __launch_bounds__(256) void k_probe(const float* __restrict__ emb)
{
    const int n = blockIdx.y;
    const float* eb = emb + (size_t)n * NCH * HW_;
    const int p = blockIdx.x * 1024 + 4 * threadIdx.x;
    float ss0 = 0.f, ss1 = 0.f, ss2 = 0.f, ss3 = 0.f;
    {
        float4 A0, A1, A2, A3, B0, B1, B2, B3;
        LD4(A, 0);  LD4(B, 4);
        STEP_SS(A); LD4(A, 8);
        STEP_SS(B); LD4(B, 12);
        STEP_SS(A); LD4(A, 16);
        STEP_SS(B); LD4(B, 20);
        STEP_SS(A); LD4(A, 24);
        STEP_SS(B); LD4(B, 28);
        STEP_SS(A); STEP_SS(B);
    }
    // keep loads live without any store (rule #17)
    asm volatile("" :: "v"(ss0), "v"(ss1), "v"(ss2), "v"(ss3));
}

extern "C" void kernel_launch(void* const* d_in, const int* in_sizes, int n_in,
                              void* d_out, int out_size, void* d_ws, size_t ws_size,
                              hipStream_t stream)
{
    const float* emb = (const float*)d_in[0];
    const int*   lab = (const int*)d_in[1];
    float* ws  = (float*)d_ws;
    float* out = (float*)d_out;

    hipMemsetAsync(d_ws, 0, WS_ZERO_FLOATS * sizeof(float), stream);

    dim3 g(HW_ / 1024, NIMG);   // 256 x 4 = 1024 blocks, 4 px/thread
    k_seg<<<g, 256, 0, stream>>>(emb, lab, ws);

    k_stats<<<NIMG, 512, 0, stream>>>(ws);

    k_intra<<<g, 256, 0, stream>>>(emb, lab, ws);

    k_final<<<1, 64, 0, stream>>>(ws, out);

    // diagnostic: pure pipelined-load floor (separate dispatch in rocprof)
    k_probe<<<g, 256, 0, stream>>>(emb);
}

// Round 7
// 99.898 us; speedup vs baseline: 2.9100x; 1.1979x over previous
//
#include <hip/hip_runtime.h>

#define HW_ 262144          // 512*512
#define NCH 32
#define NIMG 4
#define NCLS 19
#define ALPHA_ 0.05f
#define BETA_ 1.0f

// workspace float offsets
#define WS_SEG   0          // [4][19][32] class sums
#define WS_CNT   2432       // [4][19]     class counts
#define WS_MEAN  2508       // [4][19][32] class means
#define WS_MNORM 4940       // [4][19]     ||mean||^2 per class
#define WS_INUM  5016       // [4] intra numerator
#define WS_ICNT  5020       // [4] intra valid count
#define WS_IVAL  5024       // [4] per-image inter value
#define WS_ZERO_FLOATS 5028

#define REP 2
#define FXS 2097152.0f      // 2^21 fixed-point scale
#define FXI (1.0f/2097152.0f)

#define LD1(dst, c) dst = *(const float4*)(eb + (size_t)(c) * HW_ + p);
#define LDG8(g, cb) { LD1(g##0,(cb)+0) LD1(g##1,(cb)+1) LD1(g##2,(cb)+2) LD1(g##3,(cb)+3) \
                      LD1(g##4,(cb)+4) LD1(g##5,(cb)+5) LD1(g##6,(cb)+6) LD1(g##7,(cb)+7) }

#define SSACC(v) { ss0 += v.x*v.x; ss1 += v.y*v.y; ss2 += v.z*v.z; ss3 += v.w*v.w; }
#define SS8(g) { SSACC(g##0) SSACC(g##1) SSACC(g##2) SSACC(g##3) \
                 SSACC(g##4) SSACC(g##5) SSACC(g##6) SSACC(g##7) }

// ---------------- k_seg: single global read, register-resident tile ----------
// 4 px/thread, all 32 channels held in 32 named float4 registers (channel
// bases are wave-uniform -> SGPR addressing). Scatter via int32 fixed-point
// ds_add_u32 (hw one-shot), REP=2 lane-parity replicas.
__global__ __launch_bounds__(256) void k_seg(const float* __restrict__ emb,
                                             const int* __restrict__ lab,
                                             float* __restrict__ ws)
{
    const int n = blockIdx.y;
    __shared__ int segi[REP][NCLS][33];
    __shared__ int cnti[REP][NCLS];
    for (int t = threadIdx.x; t < REP * NCLS * 33; t += 256) (&segi[0][0][0])[t] = 0;
    if (threadIdx.x < REP * NCLS) (&cnti[0][0])[threadIdx.x] = 0;
    __syncthreads();

    const float* eb = emb + (size_t)n * NCH * HW_;
    const int p = blockIdx.x * 1024 + 4 * threadIdx.x;   // 4 px per thread

    int4 lv = *(const int4*)(lab + (size_t)n * HW_ + p);
    const int l0 = (lv.x == 255) ? 0 : lv.x;
    const int l1 = (lv.y == 255) ? 0 : lv.y;
    const int l2 = (lv.z == 255) ? 0 : lv.z;
    const int l3 = (lv.w == 255) ? 0 : lv.w;
    const int rep = threadIdx.x & (REP - 1);

    // load ALL 32 channels into registers (32 independent loads in flight)
    float4 Va0, Va1, Va2, Va3, Va4, Va5, Va6, Va7;
    float4 Vb0, Vb1, Vb2, Vb3, Vb4, Vb5, Vb6, Vb7;
    float4 Vc0, Vc1, Vc2, Vc3, Vc4, Vc5, Vc6, Vc7;
    float4 Vd0, Vd1, Vd2, Vd3, Vd4, Vd5, Vd6, Vd7;
    LDG8(Va, 0); LDG8(Vb, 8); LDG8(Vc, 16); LDG8(Vd, 24);

    float ss0 = 0.f, ss1 = 0.f, ss2 = 0.f, ss3 = 0.f;
    SS8(Va); SS8(Vb); SS8(Vc); SS8(Vd);

    const float rn0 = FXS / fmaxf(sqrtf(ss0), 1e-12f);
    const float rn1 = FXS / fmaxf(sqrtf(ss1), 1e-12f);
    const float rn2 = FXS / fmaxf(sqrtf(ss2), 1e-12f);
    const float rn3 = FXS / fmaxf(sqrtf(ss3), 1e-12f);

    atomicAdd(&cnti[rep][l0], 1);
    atomicAdd(&cnti[rep][l1], 1);
    atomicAdd(&cnti[rep][l2], 1);
    atomicAdd(&cnti[rep][l3], 1);

    // scatter from registers (no second global read)
#define SCAT(v, c) {                                          \
    atomicAdd(&segi[rep][l0][c], __float2int_rn(v.x * rn0));  \
    atomicAdd(&segi[rep][l1][c], __float2int_rn(v.y * rn1));  \
    atomicAdd(&segi[rep][l2][c], __float2int_rn(v.z * rn2));  \
    atomicAdd(&segi[rep][l3][c], __float2int_rn(v.w * rn3)); }
#define SC8(g, cb) { SCAT(g##0,(cb)+0) SCAT(g##1,(cb)+1) SCAT(g##2,(cb)+2) SCAT(g##3,(cb)+3) \
                     SCAT(g##4,(cb)+4) SCAT(g##5,(cb)+5) SCAT(g##6,(cb)+6) SCAT(g##7,(cb)+7) }
    SC8(Va, 0); SC8(Vb, 8); SC8(Vc, 16); SC8(Vd, 24);
    __syncthreads();

    // flush: int -> float, one global hw atomic per value
    for (int t = threadIdx.x; t < NCLS * NCH; t += 256) {
        int k = t >> 5, c = t & 31;
        float s = (float)(segi[0][k][c] + segi[1][k][c]) * FXI;
        unsafeAtomicAdd(&ws[WS_SEG + n * NCLS * NCH + t], s);
    }
    if (threadIdx.x < NCLS) {
        float s = (float)(cnti[0][threadIdx.x] + cnti[1][threadIdx.x]);
        unsafeAtomicAdd(&ws[WS_CNT + n * NCLS + threadIdx.x], s);
    }
}

// ---------------- k_stats: means, ||mean||^2, D matrix, per-image inter ------
__global__ __launch_bounds__(512) void k_stats(float* __restrict__ ws)
{
    const int n = blockIdx.x;
    __shared__ float smean[NCLS][NCH + 1];
    __shared__ float scnt[NCLS];
    __shared__ float snum, sden;
    if (threadIdx.x == 0) { snum = 0.f; sden = 0.f; }
    for (int t = threadIdx.x; t < NCLS; t += blockDim.x)
        scnt[t] = ws[WS_CNT + n * NCLS + t];
    __syncthreads();

    for (int t = threadIdx.x; t < NCLS * NCH; t += blockDim.x) {
        int k = t >> 5, c = t & 31;
        float m = ws[WS_SEG + n * NCLS * NCH + t] / (scnt[k] + 1.f);
        smean[k][c] = m;
        ws[WS_MEAN + n * NCLS * NCH + t] = m;
    }
    __syncthreads();

    if (threadIdx.x < NCLS) {
        float s = 0.f;
        #pragma unroll
        for (int c = 0; c < NCH; ++c) { float m = smean[threadIdx.x][c]; s += m * m; }
        ws[WS_MNORM + n * NCLS + threadIdx.x] = s;
    }

    for (int t = threadIdx.x; t < NCLS * NCLS; t += blockDim.x) {
        int i = t / NCLS, j = t - i * NCLS;
        float D = 0.f;
        #pragma unroll
        for (int c = 0; c < NCH; ++c) {
            float df = smean[i][c] - smean[j][c];
            D += df * df;
        }
        float pres = (scnt[i] > 0.f && scnt[j] > 0.f) ? 1.f : 0.f;
        D *= pres;
        bool im = (D < BETA_) && (D > 0.f);
        if (i >= 1 && im) {
            unsafeAtomicAdd(&sden, 1.f);
            if (j >= 1) unsafeAtomicAdd(&snum, BETA_ - D);
        }
    }
    __syncthreads();
    if (threadIdx.x == 0)
        ws[WS_IVAL + n] = snum / (sden + 1.f) * 0.5f;
}

// ---------------- k_intra: single pass, pipelined, algebraic expansion -------
#define LD4(dst, cb) {                                            \
    dst##0 = *(const float4*)(eb + (size_t)((cb)+0) * HW_ + p);   \
    dst##1 = *(const float4*)(eb + (size_t)((cb)+1) * HW_ + p);   \
    dst##2 = *(const float4*)(eb + (size_t)((cb)+2) * HW_ + p);   \
    dst##3 = *(const float4*)(eb + (size_t)((cb)+3) * HW_ + p); }

__global__ __launch_bounds__(256) void k_intra(const float* __restrict__ emb,
                                               const int* __restrict__ lab,
                                               float* __restrict__ ws)
{
    const int n = blockIdx.y;
    __shared__ float smean[NCLS][33];
    __shared__ float smn[NCLS];
    __shared__ float bnum, bcnt;
    for (int t = threadIdx.x; t < NCLS * NCH; t += 256)
        smean[t >> 5][t & 31] = ws[WS_MEAN + n * NCLS * NCH + t];
    if (threadIdx.x < NCLS) smn[threadIdx.x] = ws[WS_MNORM + n * NCLS + threadIdx.x];
    if (threadIdx.x == 0) { bnum = 0.f; bcnt = 0.f; }
    __syncthreads();

    const float* eb = emb + (size_t)n * NCH * HW_;
    const int p = blockIdx.x * 1024 + 4 * threadIdx.x;

    int4 lv = *(const int4*)(lab + (size_t)n * HW_ + p);
    const int l0 = (lv.x == 255) ? 0 : lv.x;
    const int l1 = (lv.y == 255) ? 0 : lv.y;
    const int l2 = (lv.z == 255) ? 0 : lv.z;
    const int l3 = (lv.w == 255) ? 0 : lv.w;

    float ss0 = 0.f, ss1 = 0.f, ss2 = 0.f, ss3 = 0.f;
    float dt0 = 0.f, dt1 = 0.f, dt2 = 0.f, dt3 = 0.f;
#define DOTACC(v, c) {                                  \
    float m0 = smean[l0][c], m1 = smean[l1][c];         \
    float m2 = smean[l2][c], m3 = smean[l3][c];         \
    ss0 += v.x*v.x; dt0 += v.x*m0;                      \
    ss1 += v.y*v.y; dt1 += v.y*m1;                      \
    ss2 += v.z*v.z; dt2 += v.z*m2;                      \
    ss3 += v.w*v.w; dt3 += v.w*m3; }
#define STEP_DOT(b, cb) { DOTACC(b##0, (cb)+0); DOTACC(b##1, (cb)+1); DOTACC(b##2, (cb)+2); DOTACC(b##3, (cb)+3); }
    {
        float4 A0, A1, A2, A3, B0, B1, B2, B3;
        LD4(A, 0);       LD4(B, 4);
        STEP_DOT(A, 0);  LD4(A, 8);
        STEP_DOT(B, 4);  LD4(B, 12);
        STEP_DOT(A, 8);  LD4(A, 16);
        STEP_DOT(B, 12); LD4(B, 20);
        STEP_DOT(A, 16); LD4(A, 24);
        STEP_DOT(B, 20); LD4(B, 28);
        STEP_DOT(A, 24); STEP_DOT(B, 28);
    }
    const float rn0 = 1.f / fmaxf(sqrtf(ss0), 1e-12f);
    const float rn1 = 1.f / fmaxf(sqrtf(ss1), 1e-12f);
    const float rn2 = 1.f / fmaxf(sqrtf(ss2), 1e-12f);
    const float rn3 = 1.f / fmaxf(sqrtf(ss3), 1e-12f);
    float d0 = smn[l0] - 2.f * dt0 * rn0 + ss0 * rn0 * rn0;
    float d1 = smn[l1] - 2.f * dt1 * rn1 + ss1 * rn1 * rn1;
    float d2 = smn[l2] - 2.f * dt2 * rn2 + ss2 * rn2 * rn2;
    float d3 = smn[l3] - 2.f * dt3 * rn3 + ss3 * rn3 * rn3;

    float lnum = 0.f, lcnt = 0.f;
    if (l0 > 0 && d0 > ALPHA_) { lnum += d0 - ALPHA_; lcnt += 1.f; }
    if (l1 > 0 && d1 > ALPHA_) { lnum += d1 - ALPHA_; lcnt += 1.f; }
    if (l2 > 0 && d2 > ALPHA_) { lnum += d2 - ALPHA_; lcnt += 1.f; }
    if (l3 > 0 && d3 > ALPHA_) { lnum += d3 - ALPHA_; lcnt += 1.f; }

    for (int o = 32; o > 0; o >>= 1) {
        lnum += __shfl_down(lnum, o);
        lcnt += __shfl_down(lcnt, o);
    }
    if ((threadIdx.x & 63) == 0) { unsafeAtomicAdd(&bnum, lnum); unsafeAtomicAdd(&bcnt, lcnt); }
    __syncthreads();
    if (threadIdx.x == 0) {
        unsafeAtomicAdd(&ws[WS_INUM + n], bnum);
        unsafeAtomicAdd(&ws[WS_ICNT + n], bcnt);
    }
}

// ---------------- k_final ----------------------------------------------------
__global__ void k_final(const float* __restrict__ ws, float* __restrict__ out)
{
    if (threadIdx.x == 0 && blockIdx.x == 0) {
        float intra = 0.f, inter = 0.f;
        for (int n = 0; n < NIMG; ++n) {
            intra += ws[WS_INUM + n] / (ws[WS_ICNT + n] + 1.f);
            inter += ws[WS_IVAL + n];
        }
        out[0] = intra * 0.25f;
        out[1] = inter * 0.25f;
    }
}

extern "C" void kernel_launch(void* const* d_in, const int* in_sizes, int n_in,
                              void* d_out, int out_size, void* d_ws, size_t ws_size,
                              hipStream_t stream)
{
    const float* emb = (const float*)d_in[0];
    const int*   lab = (const int*)d_in[1];
    float* ws  = (float*)d_ws;
    float* out = (float*)d_out;

    hipMemsetAsync(d_ws, 0, WS_ZERO_FLOATS * sizeof(float), stream);

    dim3 g(HW_ / 1024, NIMG);   // 256 x 4 = 1024 blocks, 4 px/thread
    k_seg<<<g, 256, 0, stream>>>(emb, lab, ws);

    k_stats<<<NIMG, 512, 0, stream>>>(ws);

    k_intra<<<g, 256, 0, stream>>>(emb, lab, ws);

    k_final<<<1, 64, 0, stream>>>(ws, out);
}

// Round 8
// 86.089 us; speedup vs baseline: 3.3768x; 1.1604x over previous
//
#include <hip/hip_runtime.h>

#define HW_ 262144          // 512*512
#define NCH 32
#define NIMG 4
#define NCLS 19
#define NBLK 256            // blocks per image (x-dim)
#define ALPHA_ 0.05f
#define BETA_ 1.0f

// workspace float offsets — every slot is WRITTEN fresh each call (no RMW,
// no zeroing needed, replay-deterministic)
#define P_SEG   0                                   // [4][19][32][256] per-block class sums
#define P_CNT   (P_SEG + NIMG*NCLS*NCH*NBLK)        // [4][19][256]     per-block counts
#define W_MEAN  (P_CNT + NIMG*NCLS*NBLK)            // [4][19][32]
#define W_MNORM (W_MEAN + NIMG*NCLS*NCH)            // [4][19]
#define W_IVAL  (W_MNORM + NIMG*NCLS)               // [4]
#define P_IN    (W_IVAL + NIMG)                     // [4][256][2] intra partials

#define REP 2
#define FXS 2097152.0f      // 2^21 fixed-point scale
#define FXI (1.0f/2097152.0f)

#define LD1(dst, c) dst = *(const float4*)(eb + (size_t)(c) * HW_ + p);
#define LDG8(g, cb) { LD1(g##0,(cb)+0) LD1(g##1,(cb)+1) LD1(g##2,(cb)+2) LD1(g##3,(cb)+3) \
                      LD1(g##4,(cb)+4) LD1(g##5,(cb)+5) LD1(g##6,(cb)+6) LD1(g##7,(cb)+7) }

#define SSACC(v) { ss0 += v.x*v.x; ss1 += v.y*v.y; ss2 += v.z*v.z; ss3 += v.w*v.w; }
#define SS8(g) { SSACC(g##0) SSACC(g##1) SSACC(g##2) SSACC(g##3) \
                 SSACC(g##4) SSACC(g##5) SSACC(g##6) SSACC(g##7) }

// ---------------- k_seg: register-resident tile -> LDS int accum -> partials -
__global__ __launch_bounds__(256) void k_seg(const float* __restrict__ emb,
                                             const int* __restrict__ lab,
                                             float* __restrict__ ws)
{
    const int n = blockIdx.y;
    const int b = blockIdx.x;
    __shared__ int segi[REP][NCLS][33];
    __shared__ int cnti[REP][NCLS];
    for (int t = threadIdx.x; t < REP * NCLS * 33; t += 256) (&segi[0][0][0])[t] = 0;
    if (threadIdx.x < REP * NCLS) (&cnti[0][0])[threadIdx.x] = 0;
    __syncthreads();

    const float* eb = emb + (size_t)n * NCH * HW_;
    const int p = b * 1024 + 4 * threadIdx.x;   // 4 px per thread

    int4 lv = *(const int4*)(lab + (size_t)n * HW_ + p);
    const int l0 = (lv.x == 255) ? 0 : lv.x;
    const int l1 = (lv.y == 255) ? 0 : lv.y;
    const int l2 = (lv.z == 255) ? 0 : lv.z;
    const int l3 = (lv.w == 255) ? 0 : lv.w;
    const int rep = threadIdx.x & (REP - 1);

    // all 32 channels in registers (32 independent float4 loads in flight)
    float4 Va0, Va1, Va2, Va3, Va4, Va5, Va6, Va7;
    float4 Vb0, Vb1, Vb2, Vb3, Vb4, Vb5, Vb6, Vb7;
    float4 Vc0, Vc1, Vc2, Vc3, Vc4, Vc5, Vc6, Vc7;
    float4 Vd0, Vd1, Vd2, Vd3, Vd4, Vd5, Vd6, Vd7;
    LDG8(Va, 0); LDG8(Vb, 8); LDG8(Vc, 16); LDG8(Vd, 24);

    float ss0 = 0.f, ss1 = 0.f, ss2 = 0.f, ss3 = 0.f;
    SS8(Va); SS8(Vb); SS8(Vc); SS8(Vd);

    const float rn0 = FXS / fmaxf(sqrtf(ss0), 1e-12f);
    const float rn1 = FXS / fmaxf(sqrtf(ss1), 1e-12f);
    const float rn2 = FXS / fmaxf(sqrtf(ss2), 1e-12f);
    const float rn3 = FXS / fmaxf(sqrtf(ss3), 1e-12f);

    atomicAdd(&cnti[rep][l0], 1);
    atomicAdd(&cnti[rep][l1], 1);
    atomicAdd(&cnti[rep][l2], 1);
    atomicAdd(&cnti[rep][l3], 1);

    // scatter from registers via native ds_add_u32 (int fixed-point)
#define SCAT(v, c) {                                          \
    atomicAdd(&segi[rep][l0][c], __float2int_rn(v.x * rn0));  \
    atomicAdd(&segi[rep][l1][c], __float2int_rn(v.y * rn1));  \
    atomicAdd(&segi[rep][l2][c], __float2int_rn(v.z * rn2));  \
    atomicAdd(&segi[rep][l3][c], __float2int_rn(v.w * rn3)); }
#define SC8(g, cb) { SCAT(g##0,(cb)+0) SCAT(g##1,(cb)+1) SCAT(g##2,(cb)+2) SCAT(g##3,(cb)+3) \
                     SCAT(g##4,(cb)+4) SCAT(g##5,(cb)+5) SCAT(g##6,(cb)+6) SCAT(g##7,(cb)+7) }
    SC8(Va, 0); SC8(Vb, 8); SC8(Vc, 16); SC8(Vd, 24);
    __syncthreads();

    // write per-block partials (plain stores — no atomics, no pre-zeroing)
    for (int t = threadIdx.x; t < NCLS * NCH; t += 256) {
        int k = t >> 5, c = t & 31;
        float s = (float)(segi[0][k][c] + segi[1][k][c]) * FXI;
        ws[P_SEG + ((size_t)n * NCLS * NCH + t) * NBLK + b] = s;
    }
    if (threadIdx.x < NCLS) {
        float s = (float)(cnti[0][threadIdx.x] + cnti[1][threadIdx.x]);
        ws[P_CNT + ((size_t)n * NCLS + threadIdx.x) * NBLK + b] = s;
    }
}

// ---------------- k_stats: reduce partials -> means, mnorm, D, inter ---------
__global__ __launch_bounds__(512) void k_stats(float* __restrict__ ws)
{
    const int n = blockIdx.x;
    __shared__ float smean[NCLS][NCH + 1];
    __shared__ float scnt[NCLS];
    __shared__ float rnum[8], rden[8];

    // counts: 19 threads each reduce a contiguous 256-float run (float4 x64)
    if (threadIdx.x < NCLS) {
        const float4* cp = (const float4*)(ws + P_CNT + ((size_t)n * NCLS + threadIdx.x) * NBLK);
        float a0 = 0.f, a1 = 0.f, a2 = 0.f, a3 = 0.f;
        #pragma unroll
        for (int i = 0; i < 64; i += 4) {
            float4 x = cp[i], y = cp[i+1], z = cp[i+2], w = cp[i+3];
            a0 += x.x + x.y + x.z + x.w;
            a1 += y.x + y.y + y.z + y.w;
            a2 += z.x + z.y + z.z + z.w;
            a3 += w.x + w.y + w.z + w.w;
        }
        scnt[threadIdx.x] = a0 + a1 + a2 + a3;
    }
    __syncthreads();

    // seg sums -> means
    for (int t = threadIdx.x; t < NCLS * NCH; t += 512) {
        const float4* sp = (const float4*)(ws + P_SEG + ((size_t)n * NCLS * NCH + t) * NBLK);
        float a0 = 0.f, a1 = 0.f, a2 = 0.f, a3 = 0.f;
        #pragma unroll
        for (int i = 0; i < 64; i += 4) {
            float4 x = sp[i], y = sp[i+1], z = sp[i+2], w = sp[i+3];
            a0 += x.x + x.y + x.z + x.w;
            a1 += y.x + y.y + y.z + y.w;
            a2 += z.x + z.y + z.z + z.w;
            a3 += w.x + w.y + w.z + w.w;
        }
        float m = (a0 + a1 + a2 + a3) / (scnt[t >> 5] + 1.f);
        smean[t >> 5][t & 31] = m;
        ws[W_MEAN + n * NCLS * NCH + t] = m;
    }
    __syncthreads();

    if (threadIdx.x < NCLS) {
        float s = 0.f;
        #pragma unroll
        for (int c = 0; c < NCH; ++c) { float m = smean[threadIdx.x][c]; s += m * m; }
        ws[W_MNORM + n * NCLS + threadIdx.x] = s;
    }

    // D matrix: one (i,j) per thread, shuffle-reduce num/den (no atomics)
    float cnum = 0.f, cden = 0.f;
    if (threadIdx.x < NCLS * NCLS) {
        int i = threadIdx.x / NCLS, j = threadIdx.x - i * NCLS;
        float D = 0.f;
        #pragma unroll
        for (int c = 0; c < NCH; ++c) {
            float df = smean[i][c] - smean[j][c];
            D += df * df;
        }
        float pres = (scnt[i] > 0.f && scnt[j] > 0.f) ? 1.f : 0.f;
        D *= pres;
        bool im = (D < BETA_) && (D > 0.f);
        if (i >= 1 && im) {
            cden = 1.f;
            if (j >= 1) cnum = BETA_ - D;
        }
    }
    for (int o = 32; o > 0; o >>= 1) {
        cnum += __shfl_down(cnum, o);
        cden += __shfl_down(cden, o);
    }
    if ((threadIdx.x & 63) == 0) { rnum[threadIdx.x >> 6] = cnum; rden[threadIdx.x >> 6] = cden; }
    __syncthreads();
    if (threadIdx.x == 0) {
        float num = 0.f, den = 0.f;
        #pragma unroll
        for (int w = 0; w < 8; ++w) { num += rnum[w]; den += rden[w]; }
        ws[W_IVAL + n] = num / (den + 1.f) * 0.5f;
    }
}

// ---------------- k_intra: single pass, pipelined, algebraic expansion -------
#define LD4(dst, cb) {                                            \
    dst##0 = *(const float4*)(eb + (size_t)((cb)+0) * HW_ + p);   \
    dst##1 = *(const float4*)(eb + (size_t)((cb)+1) * HW_ + p);   \
    dst##2 = *(const float4*)(eb + (size_t)((cb)+2) * HW_ + p);   \
    dst##3 = *(const float4*)(eb + (size_t)((cb)+3) * HW_ + p); }

__global__ __launch_bounds__(256) void k_intra(const float* __restrict__ emb,
                                               const int* __restrict__ lab,
                                               float* __restrict__ ws)
{
    const int n = blockIdx.y;
    __shared__ float smean[NCLS][33];
    __shared__ float smn[NCLS];
    __shared__ float rr[4][2];
    for (int t = threadIdx.x; t < NCLS * NCH; t += 256)
        smean[t >> 5][t & 31] = ws[W_MEAN + n * NCLS * NCH + t];
    if (threadIdx.x < NCLS) smn[threadIdx.x] = ws[W_MNORM + n * NCLS + threadIdx.x];
    __syncthreads();

    const float* eb = emb + (size_t)n * NCH * HW_;
    const int p = blockIdx.x * 1024 + 4 * threadIdx.x;

    int4 lv = *(const int4*)(lab + (size_t)n * HW_ + p);
    const int l0 = (lv.x == 255) ? 0 : lv.x;
    const int l1 = (lv.y == 255) ? 0 : lv.y;
    const int l2 = (lv.z == 255) ? 0 : lv.z;
    const int l3 = (lv.w == 255) ? 0 : lv.w;

    float ss0 = 0.f, ss1 = 0.f, ss2 = 0.f, ss3 = 0.f;
    float dt0 = 0.f, dt1 = 0.f, dt2 = 0.f, dt3 = 0.f;
#define DOTACC(v, c) {                                  \
    float m0 = smean[l0][c], m1 = smean[l1][c];         \
    float m2 = smean[l2][c], m3 = smean[l3][c];         \
    ss0 += v.x*v.x; dt0 += v.x*m0;                      \
    ss1 += v.y*v.y; dt1 += v.y*m1;                      \
    ss2 += v.z*v.z; dt2 += v.z*m2;                      \
    ss3 += v.w*v.w; dt3 += v.w*m3; }
#define STEP_DOT(b, cb) { DOTACC(b##0, (cb)+0); DOTACC(b##1, (cb)+1); DOTACC(b##2, (cb)+2); DOTACC(b##3, (cb)+3); }
    {
        float4 A0, A1, A2, A3, B0, B1, B2, B3;
        LD4(A, 0);       LD4(B, 4);
        STEP_DOT(A, 0);  LD4(A, 8);
        STEP_DOT(B, 4);  LD4(B, 12);
        STEP_DOT(A, 8);  LD4(A, 16);
        STEP_DOT(B, 12); LD4(B, 20);
        STEP_DOT(A, 16); LD4(A, 24);
        STEP_DOT(B, 20); LD4(B, 28);
        STEP_DOT(A, 24); STEP_DOT(B, 28);
    }
    const float rn0 = 1.f / fmaxf(sqrtf(ss0), 1e-12f);
    const float rn1 = 1.f / fmaxf(sqrtf(ss1), 1e-12f);
    const float rn2 = 1.f / fmaxf(sqrtf(ss2), 1e-12f);
    const float rn3 = 1.f / fmaxf(sqrtf(ss3), 1e-12f);
    float d0 = smn[l0] - 2.f * dt0 * rn0 + ss0 * rn0 * rn0;
    float d1 = smn[l1] - 2.f * dt1 * rn1 + ss1 * rn1 * rn1;
    float d2 = smn[l2] - 2.f * dt2 * rn2 + ss2 * rn2 * rn2;
    float d3 = smn[l3] - 2.f * dt3 * rn3 + ss3 * rn3 * rn3;

    float lnum = 0.f, lcnt = 0.f;
    if (l0 > 0 && d0 > ALPHA_) { lnum += d0 - ALPHA_; lcnt += 1.f; }
    if (l1 > 0 && d1 > ALPHA_) { lnum += d1 - ALPHA_; lcnt += 1.f; }
    if (l2 > 0 && d2 > ALPHA_) { lnum += d2 - ALPHA_; lcnt += 1.f; }
    if (l3 > 0 && d3 > ALPHA_) { lnum += d3 - ALPHA_; lcnt += 1.f; }

    for (int o = 32; o > 0; o >>= 1) {
        lnum += __shfl_down(lnum, o);
        lcnt += __shfl_down(lcnt, o);
    }
    if ((threadIdx.x & 63) == 0) { rr[threadIdx.x >> 6][0] = lnum; rr[threadIdx.x >> 6][1] = lcnt; }
    __syncthreads();
    if (threadIdx.x == 0) {
        float a = rr[0][0] + rr[1][0] + rr[2][0] + rr[3][0];
        float c = rr[0][1] + rr[1][1] + rr[2][1] + rr[3][1];
        ws[P_IN + ((size_t)n * NBLK + blockIdx.x) * 2 + 0] = a;
        ws[P_IN + ((size_t)n * NBLK + blockIdx.x) * 2 + 1] = c;
    }
}

// ---------------- k_final: reduce intra partials, combine --------------------
__global__ __launch_bounds__(256) void k_final(const float* __restrict__ ws,
                                               float* __restrict__ out)
{
    __shared__ float r[4][2];
    float intra = 0.f;
    for (int n = 0; n < NIMG; ++n) {
        float v0 = ws[P_IN + ((size_t)n * NBLK + threadIdx.x) * 2 + 0];
        float v1 = ws[P_IN + ((size_t)n * NBLK + threadIdx.x) * 2 + 1];
        for (int o = 32; o > 0; o >>= 1) {
            v0 += __shfl_down(v0, o);
            v1 += __shfl_down(v1, o);
        }
        if ((threadIdx.x & 63) == 0) { r[threadIdx.x >> 6][0] = v0; r[threadIdx.x >> 6][1] = v1; }
        __syncthreads();
        if (threadIdx.x == 0)
            intra += (r[0][0] + r[1][0] + r[2][0] + r[3][0]) /
                     (r[0][1] + r[1][1] + r[2][1] + r[3][1] + 1.f);
        __syncthreads();
    }
    if (threadIdx.x == 0) {
        float inter = 0.f;
        #pragma unroll
        for (int n = 0; n < NIMG; ++n) inter += ws[W_IVAL + n];
        out[0] = intra * 0.25f;
        out[1] = inter * 0.25f;
    }
}

extern "C" void kernel_launch(void* const* d_in, const int* in_sizes, int n_in,
                              void* d_out, int out_size, void* d_ws, size_t ws_size,
                              hipStream_t stream)
{
    const float* emb = (const float*)d_in[0];
    const int*   lab = (const int*)d_in[1];
    float* ws  = (float*)d_ws;
    float* out = (float*)d_out;

    // NO memset: every ws slot is written fresh each call (graph-captured
    // memset nodes were costing ~75 us of fixed blit latency).

    dim3 g(NBLK, NIMG);   // 256 x 4 = 1024 blocks, 4 px/thread
    k_seg<<<g, 256, 0, stream>>>(emb, lab, ws);

    k_stats<<<NIMG, 512, 0, stream>>>(ws);

    k_intra<<<g, 256, 0, stream>>>(emb, lab, ws);

    k_final<<<1, 256, 0, stream>>>(ws, out);
}